// Round 1
// baseline (834.932 us; speedup 1.0000x reference)
//
#include <hip/hip_runtime.h>
#include <hip/hip_bf16.h>
#include <stdint.h>

#define M_TOK 4096
#define DDIM  2048
#define HDIM  2816
#define NEXP  8
#define PMAX  9216      // 72 * 128 >= 8192 + 8*127
#define MAXTILES 72
#define NT1   44        // HDIM / 64
#define NT2   16        // DDIM / 128
#define KT1   32        // DDIM / 64
#define KT2   44        // HDIM / 64

typedef __attribute__((ext_vector_type(8))) short short8;
typedef __attribute__((ext_vector_type(4))) float f32x4;

#define GLD16(g, l) __builtin_amdgcn_global_load_lds(                              \
    (const __attribute__((address_space(1))) unsigned int*)(g),                    \
    (__attribute__((address_space(3))) unsigned int*)(l), 16, 0, 0)

__device__ __forceinline__ unsigned short f2bf(float f) {
  unsigned int u = __float_as_uint(f);
  u += 0x7fffu + ((u >> 16) & 1u);
  return (unsigned short)(u >> 16);
}

// read a 16B MFMA fragment (8 bf16 along K) from a [rows][64] bf16 LDS tile
// stored with the st-style XOR swizzle: byte ^= (row&7)<<4
__device__ __forceinline__ short8 ldsfrag(const unsigned short* base, int r, int kk) {
  int b = (r << 7) + (kk << 1);
  b ^= (r & 7) << 4;
  return *(const short8*)((const char*)base + b);
}

// ---------------- fp32 -> bf16 bulk convert ----------------
__global__ void cvt_bf16_k(const float4* __restrict__ in, ushort4* __restrict__ out, int n4) {
  int stride = gridDim.x * blockDim.x;
  for (int i = blockIdx.x * blockDim.x + threadIdx.x; i < n4; i += stride) {
    float4 v = in[i];
    ushort4 o;
    o.x = f2bf(v.x); o.y = f2bf(v.y); o.z = f2bf(v.z); o.w = f2bf(v.w);
    out[i] = o;
  }
}

// ---------------- init: tok = -1, counts/cursors = 0 ----------------
__global__ void init_k(int* __restrict__ tok, int* __restrict__ counts, int* __restrict__ cursors) {
  int i = blockIdx.x * blockDim.x + threadIdx.x;
  if (i < PMAX) tok[i] = -1;
  if (i < NEXP) { counts[i] = 0; cursors[i] = 0; }
}

// ---------------- router: logits -> softmax -> top2 -> renorm ----------------
__global__ __launch_bounds__(256) void router_k(const float* __restrict__ x,
                                                const float* __restrict__ rw,
                                                float* __restrict__ wgt,
                                                int* __restrict__ eid,
                                                int* __restrict__ counts) {
  int lane = threadIdx.x & 63;
  int wv = threadIdx.x >> 6;
  int t = blockIdx.x * 4 + wv;
  const float* xr = x + (size_t)t * DDIM;
  float acc[NEXP];
#pragma unroll
  for (int e = 0; e < NEXP; ++e) acc[e] = 0.f;
  for (int j = 0; j < DDIM / 64; ++j) {
    float xv = xr[lane + j * 64];
#pragma unroll
    for (int e = 0; e < NEXP; ++e) acc[e] += xv * rw[e * DDIM + lane + j * 64];
  }
#pragma unroll
  for (int e = 0; e < NEXP; ++e) {
#pragma unroll
    for (int s = 32; s > 0; s >>= 1) acc[e] += __shfl_xor(acc[e], s, 64);
  }
  if (lane == 0) {
    float mx = acc[0];
#pragma unroll
    for (int e = 1; e < NEXP; ++e) mx = fmaxf(mx, acc[e]);
    float p[NEXP];
#pragma unroll
    for (int e = 0; e < NEXP; ++e) p[e] = expf(acc[e] - mx);
    int e0 = 0; float p0 = p[0];
#pragma unroll
    for (int e = 1; e < NEXP; ++e) if (p[e] > p0) { p0 = p[e]; e0 = e; }
    int e1 = -1; float p1 = -1.f;
#pragma unroll
    for (int e = 0; e < NEXP; ++e) if (e != e0 && p[e] > p1) { p1 = p[e]; e1 = e; }
    float s = p0 + p1;
    wgt[2 * t] = p0 / s; wgt[2 * t + 1] = p1 / s;
    eid[2 * t] = e0;     eid[2 * t + 1] = e1;
    atomicAdd(&counts[e0], 1);
    atomicAdd(&counts[e1], 1);
  }
}

// ---------------- offsets + tile map (single thread, tiny) ----------------
__global__ void offsets_k(const int* __restrict__ counts, int* __restrict__ offs,
                          int* __restrict__ tile2exp, int* __restrict__ tilerow,
                          int* __restrict__ ntiles) {
  if (threadIdx.x == 0 && blockIdx.x == 0) {
    int o = 0, nt = 0;
    for (int e = 0; e < NEXP; ++e) {
      offs[e] = o;
      int c = counts[e];
      int pt = (c + 127) >> 7;
      for (int i = 0; i < pt; ++i) { tile2exp[nt] = e; tilerow[nt] = o + i * 128; ++nt; }
      o += pt << 7;
    }
    offs[NEXP] = o;
    ntiles[0] = nt;
  }
}

// ---------------- scatter tokens into per-expert slots ----------------
__global__ void scatter_k(const int* __restrict__ eid, const int* __restrict__ offs,
                          int* __restrict__ cursors, int* __restrict__ tok,
                          int* __restrict__ slot) {
  int t = blockIdx.x * blockDim.x + threadIdx.x;
  if (t >= M_TOK) return;
#pragma unroll
  for (int k = 0; k < 2; ++k) {
    int e = eid[2 * t + k];
    int p = offs[e] + atomicAdd(&cursors[e], 1);
    tok[p] = t;
    slot[2 * t + k] = p;
  }
}

// ---------------- GEMM1: h = silu(x@w1g^T) * (x@w1u^T), bf16 out ----------------
// tile: 128 rows (slots) x 64 h-cols, BK=64, 4 waves each 64x32
__global__ __launch_bounds__(256) void gemm1_k(const unsigned short* __restrict__ xb,
                                               const unsigned short* __restrict__ w1b,
                                               const int* __restrict__ tok,
                                               const int* __restrict__ tile2exp,
                                               const int* __restrict__ tilerow,
                                               const int* __restrict__ ntiles,
                                               unsigned short* __restrict__ h) {
  __shared__ unsigned short lA[128 * 64];
  __shared__ unsigned short lBg[64 * 64];
  __shared__ unsigned short lBu[64 * 64];
  int mt = blockIdx.x;
  if (mt >= ntiles[0]) return;
  int e  = tile2exp[mt];
  int r0 = tilerow[mt];
  int n0 = blockIdx.y * 64;
  int tid = threadIdx.x;
  int lane = tid & 63, wv = tid >> 6;

  int srow = tid >> 3;                   // 0..31
  int g16 = (tid & 7) ^ (srow & 7);      // source 16B-granule (swizzle pre-applied)
  const char* aptr[4];
#pragma unroll
  for (int i = 0; i < 4; ++i) {
    int p = r0 + i * 32 + srow;
    int t = tok[p]; if (t < 0) t = 0;
    aptr[i] = (const char*)xb + ((size_t)t * DDIM + (size_t)g16 * 8) * 2;
  }
  const char* bgptr[2]; const char* buptr[2];
#pragma unroll
  for (int i = 0; i < 2; ++i) {
    size_t rg = (size_t)e * (2 * HDIM) + n0 + i * 32 + srow;
    bgptr[i] = (const char*)w1b + (rg * DDIM + (size_t)g16 * 8) * 2;
    buptr[i] = (const char*)w1b + ((rg + HDIM) * DDIM + (size_t)g16 * 8) * 2;
  }
  char* ldA  = (char*)lA  + tid * 16;
  char* ldBg = (char*)lBg + tid * 16;
  char* ldBu = (char*)lBu + tid * 16;

  f32x4 accg[4][2], accu[4][2];
#pragma unroll
  for (int i = 0; i < 4; ++i)
#pragma unroll
    for (int j = 0; j < 2; ++j) { accg[i][j] = (f32x4)(0.f); accu[i][j] = (f32x4)(0.f); }

  int row0w = (wv >> 1) * 64, col0w = (wv & 1) * 32;
  int l15 = lane & 15, kq = (lane >> 4) * 8;

  for (int kt = 0; kt < KT1; ++kt) {
    __syncthreads();
    int kb = kt * 128;   // 64 bf16 = 128 bytes per row chunk
#pragma unroll
    for (int i = 0; i < 4; ++i) GLD16(aptr[i] + kb, ldA + i * 4096);
#pragma unroll
    for (int i = 0; i < 2; ++i) { GLD16(bgptr[i] + kb, ldBg + i * 4096); GLD16(buptr[i] + kb, ldBu + i * 4096); }
    __syncthreads();
#pragma unroll
    for (int ks = 0; ks < 2; ++ks) {
      int kk = ks * 32 + kq;
      short8 a[4], bg[2], bu[2];
#pragma unroll
      for (int i = 0; i < 4; ++i) a[i] = ldsfrag(lA, row0w + i * 16 + l15, kk);
#pragma unroll
      for (int i = 0; i < 2; ++i) {
        bg[i] = ldsfrag(lBg, col0w + i * 16 + l15, kk);
        bu[i] = ldsfrag(lBu, col0w + i * 16 + l15, kk);
      }
#pragma unroll
      for (int mi = 0; mi < 4; ++mi)
#pragma unroll
        for (int ni = 0; ni < 2; ++ni) {
          accg[mi][ni] = __builtin_amdgcn_mfma_f32_16x16x32_bf16(a[mi], bg[ni], accg[mi][ni], 0, 0, 0);
          accu[mi][ni] = __builtin_amdgcn_mfma_f32_16x16x32_bf16(a[mi], bu[ni], accu[mi][ni], 0, 0, 0);
        }
    }
  }
  // epilogue: silu(g)*u -> bf16 h
  int rbase = (lane >> 4) * 4;
#pragma unroll
  for (int mi = 0; mi < 4; ++mi)
#pragma unroll
    for (int ni = 0; ni < 2; ++ni)
#pragma unroll
      for (int j = 0; j < 4; ++j) {
        int rr = row0w + mi * 16 + rbase + j;
        int cc = col0w + ni * 16 + l15;
        float g = accg[mi][ni][j], u = accu[mi][ni][j];
        float sv = g / (1.f + expf(-g));
        h[(size_t)(r0 + rr) * HDIM + n0 + cc] = f2bf(sv * u);
      }
}

// ---------------- GEMM2: yp = h @ w2^T (fp32 out, unweighted) ----------------
// tile: 128 rows x 128 cols, BK=64, 4 waves each 64x64
__global__ __launch_bounds__(256) void gemm2_k(const unsigned short* __restrict__ h,
                                               const unsigned short* __restrict__ w2b,
                                               const int* __restrict__ tile2exp,
                                               const int* __restrict__ tilerow,
                                               const int* __restrict__ ntiles,
                                               float* __restrict__ yp) {
  __shared__ unsigned short lA[128 * 64];
  __shared__ unsigned short lB[128 * 64];
  int mt = blockIdx.x;
  if (mt >= ntiles[0]) return;
  int e  = tile2exp[mt];
  int r0 = tilerow[mt];
  int n0 = blockIdx.y * 128;
  int tid = threadIdx.x;
  int lane = tid & 63, wv = tid >> 6;

  int srow = tid >> 3;
  int g16 = (tid & 7) ^ (srow & 7);
  const char* aptr[4]; const char* bptr[4];
#pragma unroll
  for (int i = 0; i < 4; ++i) {
    aptr[i] = (const char*)h + ((size_t)(r0 + i * 32 + srow) * HDIM + (size_t)g16 * 8) * 2;
    bptr[i] = (const char*)w2b + (((size_t)e * DDIM + n0 + i * 32 + srow) * HDIM + (size_t)g16 * 8) * 2;
  }
  char* ldA = (char*)lA + tid * 16;
  char* ldB = (char*)lB + tid * 16;

  f32x4 acc[4][4];
#pragma unroll
  for (int i = 0; i < 4; ++i)
#pragma unroll
    for (int j = 0; j < 4; ++j) acc[i][j] = (f32x4)(0.f);

  int row0w = (wv >> 1) * 64, col0w = (wv & 1) * 64;
  int l15 = lane & 15, kq = (lane >> 4) * 8;

  for (int kt = 0; kt < KT2; ++kt) {
    __syncthreads();
    int kb = kt * 128;
#pragma unroll
    for (int i = 0; i < 4; ++i) { GLD16(aptr[i] + kb, ldA + i * 4096); GLD16(bptr[i] + kb, ldB + i * 4096); }
    __syncthreads();
#pragma unroll
    for (int ks = 0; ks < 2; ++ks) {
      int kk = ks * 32 + kq;
      short8 a[4], b[4];
#pragma unroll
      for (int i = 0; i < 4; ++i) a[i] = ldsfrag(lA, row0w + i * 16 + l15, kk);
#pragma unroll
      for (int i = 0; i < 4; ++i) b[i] = ldsfrag(lB, col0w + i * 16 + l15, kk);
#pragma unroll
      for (int mi = 0; mi < 4; ++mi)
#pragma unroll
        for (int ni = 0; ni < 4; ++ni)
          acc[mi][ni] = __builtin_amdgcn_mfma_f32_16x16x32_bf16(a[mi], b[ni], acc[mi][ni], 0, 0, 0);
    }
  }
  int rbase = (lane >> 4) * 4;
#pragma unroll
  for (int mi = 0; mi < 4; ++mi)
#pragma unroll
    for (int ni = 0; ni < 4; ++ni)
#pragma unroll
      for (int j = 0; j < 4; ++j) {
        int rr = row0w + mi * 16 + rbase + j;
        int cc = col0w + ni * 16 + l15;
        yp[(size_t)(r0 + rr) * DDIM + n0 + cc] = acc[mi][ni][j];
      }
}

// ---------------- combine: y = w0*yp[s0] + w1*yp[s1] + bias ----------------
__global__ void combine_k(const float* __restrict__ yp, const float* __restrict__ wgt,
                          const int* __restrict__ slot, const float* __restrict__ bias,
                          float* __restrict__ out) {
  int idx = blockIdx.x * blockDim.x + threadIdx.x;   // over M * 512 float4s
  int t = idx >> 9, q = idx & 511;
  float w0 = wgt[2 * t], w1 = wgt[2 * t + 1];
  int s0 = slot[2 * t], s1 = slot[2 * t + 1];
  float4 av = ((const float4*)(yp + (size_t)s0 * DDIM))[q];
  float4 bv = ((const float4*)(yp + (size_t)s1 * DDIM))[q];
  float4 bi = ((const float4*)bias)[q];
  float4 o;
  o.x = w0 * av.x + w1 * bv.x + bi.x;
  o.y = w0 * av.y + w1 * bv.y + bi.y;
  o.z = w0 * av.z + w1 * bv.z + bi.z;
  o.w = w0 * av.w + w1 * bv.w + bi.w;
  ((float4*)out)[idx] = o;
}

extern "C" void kernel_launch(void* const* d_in, const int* in_sizes, int n_in,
                              void* d_out, int out_size, void* d_ws, size_t ws_size,
                              hipStream_t stream) {
  const float* x    = (const float*)d_in[0];
  const float* w1   = (const float*)d_in[1];
  const float* w2   = (const float*)d_in[2];
  const float* rw   = (const float*)d_in[3];
  const float* bias = (const float*)d_in[4];
  float* out = (float*)d_out;

  char* ws = (char*)d_ws;
  size_t off = 0;
  auto alloc = [&](size_t bytes) -> void* {
    void* p = ws + off;
    off = (off + bytes + 255) & ~(size_t)255;
    return p;
  };
  unsigned short* w1b = (unsigned short*)alloc((size_t)NEXP * 2 * HDIM * DDIM * 2);
  unsigned short* w2b = (unsigned short*)alloc((size_t)NEXP * DDIM * HDIM * 2);
  unsigned short* xb  = (unsigned short*)alloc((size_t)M_TOK * DDIM * 2);
  unsigned short* h   = (unsigned short*)alloc((size_t)PMAX * HDIM * 2);
  float* yp           = (float*)alloc((size_t)PMAX * DDIM * 4);
  float* wgt          = (float*)alloc((size_t)M_TOK * 2 * 4);
  int* eid            = (int*)alloc((size_t)M_TOK * 2 * 4);
  int* slot           = (int*)alloc((size_t)M_TOK * 2 * 4);
  int* tok            = (int*)alloc((size_t)PMAX * 4);
  int* counts         = (int*)alloc(64 * 4);
  int* cursors        = (int*)alloc(64 * 4);
  int* offs           = (int*)alloc(64 * 4);
  int* ntiles         = (int*)alloc(64 * 4);
  int* tile2exp       = (int*)alloc(128 * 4);
  int* tilerow        = (int*)alloc(128 * 4);

  hipLaunchKernelGGL(init_k, dim3((PMAX + 255) / 256), dim3(256), 0, stream, tok, counts, cursors);
  hipLaunchKernelGGL(cvt_bf16_k, dim3(2048), dim3(256), 0, stream,
                     (const float4*)w1, (ushort4*)w1b, (int)((size_t)NEXP * 2 * HDIM * DDIM / 4));
  hipLaunchKernelGGL(cvt_bf16_k, dim3(2048), dim3(256), 0, stream,
                     (const float4*)w2, (ushort4*)w2b, (int)((size_t)NEXP * DDIM * HDIM / 4));
  hipLaunchKernelGGL(cvt_bf16_k, dim3(2048), dim3(256), 0, stream,
                     (const float4*)x, (ushort4*)xb, (int)((size_t)M_TOK * DDIM / 4));
  hipLaunchKernelGGL(router_k, dim3(M_TOK / 4), dim3(256), 0, stream, x, rw, wgt, eid, counts);
  hipLaunchKernelGGL(offsets_k, dim3(1), dim3(64), 0, stream, counts, offs, tile2exp, tilerow, ntiles);
  hipLaunchKernelGGL(scatter_k, dim3((M_TOK + 255) / 256), dim3(256), 0, stream, eid, offs, cursors, tok, slot);
  hipLaunchKernelGGL(gemm1_k, dim3(MAXTILES, NT1), dim3(256), 0, stream, xb, w1b, tok, tile2exp, tilerow, ntiles, h);
  hipLaunchKernelGGL(gemm2_k, dim3(MAXTILES, NT2), dim3(256), 0, stream, h, w2b, tile2exp, tilerow, ntiles, yp);
  hipLaunchKernelGGL(combine_k, dim3(M_TOK * (DDIM / 4) / 256), dim3(256), 0, stream, yp, wgt, slot, bias, out);
}

// Round 2
// 763.509 us; speedup vs baseline: 1.0935x; 1.0935x over previous
//
#include <hip/hip_runtime.h>
#include <hip/hip_bf16.h>
#include <stdint.h>

#define M_TOK 4096
#define DDIM  2048
#define HDIM  2816
#define NEXP  8
#define PMAX  10240     // 40 * 256 >= 8192 + 8*255
#define MAXTILES 40
#define NB1   22        // HDIM / 128 gate-col blocks (B tile = 128 gate + 128 up rows)
#define NB2   8         // DDIM / 256
#define NT1   64        // DDIM / 32
#define NT2   88        // HDIM / 32

typedef __attribute__((ext_vector_type(8))) short short8;
typedef __attribute__((ext_vector_type(4))) float f32x4;

#define GLD16(g, l) __builtin_amdgcn_global_load_lds(                              \
    (const __attribute__((address_space(1))) unsigned int*)(g),                    \
    (__attribute__((address_space(3))) unsigned int*)(l), 16, 0, 0)

#define VMCNT(n) asm volatile("s_waitcnt vmcnt(" #n ")" ::: "memory")

__device__ __forceinline__ unsigned short f2bf(float f) {
  unsigned int u = __float_as_uint(f);
  u += 0x7fffu + ((u >> 16) & 1u);
  return (unsigned short)(u >> 16);
}
__device__ __forceinline__ float bf2f(unsigned short u) {
  return __uint_as_float(((unsigned)u) << 16);
}

// One pipeline phase: wait tile TT landed (counted vmcnt, never 0 in steady
// state), barrier, issue stage of tile TT+3 into buffer (TT+3)%4, ds_read
// tile TT fragments, 32 MFMA. Buffer safety: the barrier separates this
// phase's stage-issue from all waves' ds_reads of tile TT-1 (same buffer).
#define PHASE(TT, VM, STG)                                                       \
  {                                                                              \
    VMCNT(VM);                                                                   \
    __builtin_amdgcn_s_barrier();                                                \
    asm volatile("" ::: "memory");                                               \
    if (STG) {                                                                   \
      int st_ = (TT) + 3;                                                        \
      int t4s_ = st_ & 3;                                                        \
      size_t kb_ = (size_t)st_ * 64;                                             \
      GLD16(aS0 + kb_, ldsp + t4s_ * 16384 + aD0);                               \
      GLD16(aS1 + kb_, ldsp + t4s_ * 16384 + aD1);                               \
      GLD16(bS0 + kb_, ldsp + 65536 + t4s_ * 16384 + aD0);                       \
      GLD16(bS1 + kb_, ldsp + 65536 + t4s_ * 16384 + aD1);                       \
    }                                                                            \
    {                                                                            \
      int t4_ = (TT) & 3;                                                        \
      const char* ab_ = ldsp + t4_ * 16384;                                      \
      const char* bb_ = ldsp + 65536 + t4_ * 16384;                              \
      short8 av_[8], bv_[4];                                                     \
      _Pragma("unroll") for (int mi = 0; mi < 8; ++mi)                           \
        av_[mi] = *(const short8*)(ab_ + aoff[mi]);                              \
      _Pragma("unroll") for (int ni = 0; ni < 4; ++ni)                           \
        bv_[ni] = *(const short8*)(bb_ + boff[ni]);                              \
      __builtin_amdgcn_s_setprio(1);                                             \
      _Pragma("unroll") for (int mi = 0; mi < 8; ++mi)                           \
        _Pragma("unroll") for (int ni = 0; ni < 4; ++ni)                         \
          acc[mi][ni] = __builtin_amdgcn_mfma_f32_16x16x32_bf16(av_[mi], bv_[ni], acc[mi][ni], 0, 0, 0); \
      __builtin_amdgcn_s_setprio(0);                                             \
    }                                                                            \
  }

// ---------------- fp32 -> bf16 bulk convert ----------------
__global__ void cvt_bf16_k(const float4* __restrict__ in, ushort4* __restrict__ out, int n4) {
  int stride = gridDim.x * blockDim.x;
  for (int i = blockIdx.x * blockDim.x + threadIdx.x; i < n4; i += stride) {
    float4 v = in[i];
    ushort4 o;
    o.x = f2bf(v.x); o.y = f2bf(v.y); o.z = f2bf(v.z); o.w = f2bf(v.w);
    out[i] = o;
  }
}

// ---------------- init ----------------
__global__ void init_k(int* __restrict__ tok, int* __restrict__ counts, int* __restrict__ cursors) {
  int i = blockIdx.x * blockDim.x + threadIdx.x;
  if (i < PMAX) tok[i] = -1;
  if (i < NEXP) { counts[i] = 0; cursors[i] = 0; }
}

// ---------------- router ----------------
__global__ __launch_bounds__(256) void router_k(const float* __restrict__ x,
                                                const float* __restrict__ rw,
                                                float* __restrict__ wgt,
                                                int* __restrict__ eid,
                                                int* __restrict__ counts) {
  int lane = threadIdx.x & 63;
  int wv = threadIdx.x >> 6;
  int t = blockIdx.x * 4 + wv;
  const float* xr = x + (size_t)t * DDIM;
  float acc[NEXP];
#pragma unroll
  for (int e = 0; e < NEXP; ++e) acc[e] = 0.f;
  for (int j = 0; j < DDIM / 64; ++j) {
    float xv = xr[lane + j * 64];
#pragma unroll
    for (int e = 0; e < NEXP; ++e) acc[e] += xv * rw[e * DDIM + lane + j * 64];
  }
#pragma unroll
  for (int e = 0; e < NEXP; ++e) {
#pragma unroll
    for (int s = 32; s > 0; s >>= 1) acc[e] += __shfl_xor(acc[e], s, 64);
  }
  if (lane == 0) {
    float mx = acc[0];
#pragma unroll
    for (int e = 1; e < NEXP; ++e) mx = fmaxf(mx, acc[e]);
    float p[NEXP];
#pragma unroll
    for (int e = 0; e < NEXP; ++e) p[e] = expf(acc[e] - mx);
    int e0 = 0; float p0 = p[0];
#pragma unroll
    for (int e = 1; e < NEXP; ++e) if (p[e] > p0) { p0 = p[e]; e0 = e; }
    int e1 = -1; float p1 = -1.f;
#pragma unroll
    for (int e = 0; e < NEXP; ++e) if (e != e0 && p[e] > p1) { p1 = p[e]; e1 = e; }
    float s = p0 + p1;
    wgt[2 * t] = p0 / s; wgt[2 * t + 1] = p1 / s;
    eid[2 * t] = e0;     eid[2 * t + 1] = e1;
    atomicAdd(&counts[e0], 1);
    atomicAdd(&counts[e1], 1);
  }
}

// ---------------- offsets + tile map (256-row tiles) ----------------
__global__ void offsets_k(const int* __restrict__ counts, int* __restrict__ offs,
                          int* __restrict__ tile2exp, int* __restrict__ tilerow,
                          int* __restrict__ ntiles) {
  if (threadIdx.x == 0 && blockIdx.x == 0) {
    int o = 0, nt = 0;
    for (int e = 0; e < NEXP; ++e) {
      offs[e] = o;
      int c = counts[e];
      int pt = (c + 255) >> 8;
      for (int i = 0; i < pt; ++i) { tile2exp[nt] = e; tilerow[nt] = o + i * 256; ++nt; }
      o += pt << 8;
    }
    offs[NEXP] = o;
    ntiles[0] = nt;
  }
}

// ---------------- scatter ----------------
__global__ void scatter_k(const int* __restrict__ eid, const int* __restrict__ offs,
                          int* __restrict__ cursors, int* __restrict__ tok,
                          int* __restrict__ slot) {
  int t = blockIdx.x * blockDim.x + threadIdx.x;
  if (t >= M_TOK) return;
#pragma unroll
  for (int k = 0; k < 2; ++k) {
    int e = eid[2 * t + k];
    int p = offs[e] + atomicAdd(&cursors[e], 1);
    tok[p] = t;
    slot[2 * t + k] = p;
  }
}

// ---------------- GEMM1: 256 slots x (128 gate + 128 up) cols, K=2048 ----------------
// 8 waves (2M x 4N), per-wave 128x64. wn<2 holds gate, wn>=2 holds up.
// Epilogue: up waves dump acc to LDS, gate waves compute silu(g)*u -> h (bf16).
__global__ __launch_bounds__(512, 2) void gemm1_k(const unsigned short* __restrict__ xb,
                                                  const unsigned short* __restrict__ w1b,
                                                  const int* __restrict__ tok,
                                                  const int* __restrict__ tile2exp,
                                                  const int* __restrict__ tilerow,
                                                  const int* __restrict__ ntiles,
                                                  unsigned short* __restrict__ h) {
  __shared__ char ldsp[131072];
  int mt = blockIdx.x;
  if (mt >= ntiles[0]) return;
  int e = tile2exp[mt], r0 = tilerow[mt];
  int n0 = blockIdx.y * 128;
  int tid = threadIdx.x, lane = tid & 63;
  int wv = tid >> 6, wm = wv >> 2, wn = wv & 3;
  int l15 = lane & 15, g = lane >> 4;

  // staging: thread owns LDS 16B slots s0=tid, s1=512+tid (linear dest);
  // global source granule is inverse-swizzled so reads can use the swizzle.
  int row0 = tid >> 2, g0 = (tid & 3) ^ ((row0 >> 1) & 3);
  int s1i = 512 + tid;
  int row1 = s1i >> 2, g1 = (s1i & 3) ^ ((row1 >> 1) & 3);
  int t0 = tok[r0 + row0]; if (t0 < 0) t0 = 0;
  int t1 = tok[r0 + row1]; if (t1 < 0) t1 = 0;
  const char* aS0 = (const char*)xb + (size_t)t0 * (DDIM * 2) + g0 * 16;
  const char* aS1 = (const char*)xb + (size_t)t1 * (DDIM * 2) + g1 * 16;
  size_t w1r0 = (size_t)e * (2 * HDIM) +
                (row0 < 128 ? (size_t)(n0 + row0) : (size_t)(HDIM + n0 + row0 - 128));
  size_t w1r1 = (size_t)e * (2 * HDIM) +
                (row1 < 128 ? (size_t)(n0 + row1) : (size_t)(HDIM + n0 + row1 - 128));
  const char* bS0 = (const char*)w1b + w1r0 * (DDIM * 2) + g0 * 16;
  const char* bS1 = (const char*)w1b + w1r1 * (DDIM * 2) + g1 * 16;
  int aD0 = tid * 16, aD1 = 8192 + tid * 16;

  // fragment read byte offsets (within a 16KB buffer), swizzled
  int aoff[8], boff[4];
#pragma unroll
  for (int mi = 0; mi < 8; ++mi) {
    int r = wm * 128 + mi * 16 + l15;
    aoff[mi] = r * 64 + ((g ^ ((r >> 1) & 3)) * 16);
  }
#pragma unroll
  for (int ni = 0; ni < 4; ++ni) {
    int r = wn * 64 + ni * 16 + l15;
    boff[ni] = r * 64 + ((g ^ ((r >> 1) & 3)) * 16);
  }

  f32x4 acc[8][4];
#pragma unroll
  for (int mi = 0; mi < 8; ++mi)
#pragma unroll
    for (int ni = 0; ni < 4; ++ni) acc[mi][ni] = (f32x4)(0.f);

  // prologue: stage tiles 0,1,2
#pragma unroll
  for (int t = 0; t < 3; ++t) {
    GLD16(aS0 + (size_t)t * 64, ldsp + t * 16384 + aD0);
    GLD16(aS1 + (size_t)t * 64, ldsp + t * 16384 + aD1);
    GLD16(bS0 + (size_t)t * 64, ldsp + 65536 + t * 16384 + aD0);
    GLD16(bS1 + (size_t)t * 64, ldsp + 65536 + t * 16384 + aD1);
  }

  int T = 0;
  for (; T + 3 < NT1; ++T) PHASE(T, 8, 1);
  PHASE(T, 8, 0); ++T;
  PHASE(T, 4, 0); ++T;
  PHASE(T, 0, 0);

  // epilogue: cross-wave GLU pairing through LDS (exactly 128 KB f32 [256][128])
  __syncthreads();
  float* xch = (float*)ldsp;
  int rbase = (lane >> 4) * 4;
  if (wn >= 2) {
    int uc0 = (wn - 2) * 64;
#pragma unroll
    for (int mi = 0; mi < 8; ++mi)
#pragma unroll
      for (int ni = 0; ni < 4; ++ni)
#pragma unroll
        for (int j = 0; j < 4; ++j) {
          int r = wm * 128 + mi * 16 + rbase + j;
          int c = uc0 + ni * 16 + l15;
          xch[r * 128 + c] = acc[mi][ni][j];
        }
  }
  __syncthreads();
  if (wn < 2) {
#pragma unroll
    for (int mi = 0; mi < 8; ++mi)
#pragma unroll
      for (int ni = 0; ni < 4; ++ni)
#pragma unroll
        for (int j = 0; j < 4; ++j) {
          int r = wm * 128 + mi * 16 + rbase + j;
          int c = wn * 64 + ni * 16 + l15;
          float gg = acc[mi][ni][j];
          float u = xch[r * 128 + c];
          float sv = gg / (1.f + expf(-gg));
          h[(size_t)(r0 + r) * HDIM + n0 + c] = f2bf(sv * u);
        }
  }
}

// ---------------- GEMM2: 256 slots x 256 D-cols, K=2816, yp bf16 ----------------
__global__ __launch_bounds__(512, 2) void gemm2_k(const unsigned short* __restrict__ h,
                                                  const unsigned short* __restrict__ w2b,
                                                  const int* __restrict__ tile2exp,
                                                  const int* __restrict__ tilerow,
                                                  const int* __restrict__ ntiles,
                                                  unsigned short* __restrict__ yp) {
  __shared__ char ldsp[131072];
  int mt = blockIdx.x;
  if (mt >= ntiles[0]) return;
  int e = tile2exp[mt], r0 = tilerow[mt];
  int n0 = blockIdx.y * 256;
  int tid = threadIdx.x, lane = tid & 63;
  int wv = tid >> 6, wm = wv >> 2, wn = wv & 3;
  int l15 = lane & 15, g = lane >> 4;

  int row0 = tid >> 2, g0 = (tid & 3) ^ ((row0 >> 1) & 3);
  int s1i = 512 + tid;
  int row1 = s1i >> 2, g1 = (s1i & 3) ^ ((row1 >> 1) & 3);
  const char* aS0 = (const char*)h + (size_t)(r0 + row0) * (HDIM * 2) + g0 * 16;
  const char* aS1 = (const char*)h + (size_t)(r0 + row1) * (HDIM * 2) + g1 * 16;
  const char* bS0 = (const char*)w2b + ((size_t)e * DDIM + n0 + row0) * (HDIM * 2) + g0 * 16;
  const char* bS1 = (const char*)w2b + ((size_t)e * DDIM + n0 + row1) * (HDIM * 2) + g1 * 16;
  int aD0 = tid * 16, aD1 = 8192 + tid * 16;

  int aoff[8], boff[4];
#pragma unroll
  for (int mi = 0; mi < 8; ++mi) {
    int r = wm * 128 + mi * 16 + l15;
    aoff[mi] = r * 64 + ((g ^ ((r >> 1) & 3)) * 16);
  }
#pragma unroll
  for (int ni = 0; ni < 4; ++ni) {
    int r = wn * 64 + ni * 16 + l15;
    boff[ni] = r * 64 + ((g ^ ((r >> 1) & 3)) * 16);
  }

  f32x4 acc[8][4];
#pragma unroll
  for (int mi = 0; mi < 8; ++mi)
#pragma unroll
    for (int ni = 0; ni < 4; ++ni) acc[mi][ni] = (f32x4)(0.f);

#pragma unroll
  for (int t = 0; t < 3; ++t) {
    GLD16(aS0 + (size_t)t * 64, ldsp + t * 16384 + aD0);
    GLD16(aS1 + (size_t)t * 64, ldsp + t * 16384 + aD1);
    GLD16(bS0 + (size_t)t * 64, ldsp + 65536 + t * 16384 + aD0);
    GLD16(bS1 + (size_t)t * 64, ldsp + 65536 + t * 16384 + aD1);
  }

  int T = 0;
  for (; T + 3 < NT2; ++T) PHASE(T, 8, 1);
  PHASE(T, 8, 0); ++T;
  PHASE(T, 4, 0); ++T;
  PHASE(T, 0, 0);

  int rbase = (lane >> 4) * 4;
#pragma unroll
  for (int mi = 0; mi < 8; ++mi)
#pragma unroll
    for (int ni = 0; ni < 4; ++ni)
#pragma unroll
      for (int j = 0; j < 4; ++j) {
        int r = r0 + wm * 128 + mi * 16 + rbase + j;
        int c = n0 + wn * 64 + ni * 16 + l15;
        yp[(size_t)r * DDIM + c] = f2bf(acc[mi][ni][j]);
      }
}

// ---------------- combine: y = w0*yp[s0] + w1*yp[s1] + bias ----------------
__global__ void combine_k(const unsigned short* __restrict__ yp, const float* __restrict__ wgt,
                          const int* __restrict__ slot, const float* __restrict__ bias,
                          float* __restrict__ out) {
  int idx = blockIdx.x * blockDim.x + threadIdx.x;   // M_TOK * 256 threads, 8 cols each
  int t = idx >> 8, q = (idx & 255) * 8;
  float w0 = wgt[2 * t], w1 = wgt[2 * t + 1];
  int s0 = slot[2 * t], s1 = slot[2 * t + 1];
  short8 a8 = *(const short8*)(yp + (size_t)s0 * DDIM + q);
  short8 b8 = *(const short8*)(yp + (size_t)s1 * DDIM + q);
  float* op = out + (size_t)t * DDIM + q;
#pragma unroll
  for (int k = 0; k < 8; ++k) {
    float av = bf2f((unsigned short)a8[k]);
    float bv = bf2f((unsigned short)b8[k]);
    op[k] = w0 * av + w1 * bv + bias[q + k];
  }
}

extern "C" void kernel_launch(void* const* d_in, const int* in_sizes, int n_in,
                              void* d_out, int out_size, void* d_ws, size_t ws_size,
                              hipStream_t stream) {
  const float* x    = (const float*)d_in[0];
  const float* w1   = (const float*)d_in[1];
  const float* w2   = (const float*)d_in[2];
  const float* rw   = (const float*)d_in[3];
  const float* bias = (const float*)d_in[4];
  float* out = (float*)d_out;

  char* ws = (char*)d_ws;
  size_t off = 0;
  auto alloc = [&](size_t bytes) -> void* {
    void* p = ws + off;
    off = (off + bytes + 255) & ~(size_t)255;
    return p;
  };
  unsigned short* w1b = (unsigned short*)alloc((size_t)NEXP * 2 * HDIM * DDIM * 2);
  unsigned short* w2b = (unsigned short*)alloc((size_t)NEXP * DDIM * HDIM * 2);
  unsigned short* xb  = (unsigned short*)alloc((size_t)M_TOK * DDIM * 2);
  unsigned short* h   = (unsigned short*)alloc((size_t)PMAX * HDIM * 2);
  unsigned short* yp  = (unsigned short*)alloc((size_t)PMAX * DDIM * 2);
  float* wgt          = (float*)alloc((size_t)M_TOK * 2 * 4);
  int* eid            = (int*)alloc((size_t)M_TOK * 2 * 4);
  int* slot           = (int*)alloc((size_t)M_TOK * 2 * 4);
  int* tok            = (int*)alloc((size_t)PMAX * 4);
  int* counts         = (int*)alloc(64 * 4);
  int* cursors        = (int*)alloc(64 * 4);
  int* offs           = (int*)alloc(64 * 4);
  int* ntiles         = (int*)alloc(64 * 4);
  int* tile2exp       = (int*)alloc(128 * 4);
  int* tilerow        = (int*)alloc(128 * 4);

  hipLaunchKernelGGL(init_k, dim3((PMAX + 255) / 256), dim3(256), 0, stream, tok, counts, cursors);
  hipLaunchKernelGGL(cvt_bf16_k, dim3(2048), dim3(256), 0, stream,
                     (const float4*)w1, (ushort4*)w1b, (int)((size_t)NEXP * 2 * HDIM * DDIM / 4));
  hipLaunchKernelGGL(cvt_bf16_k, dim3(2048), dim3(256), 0, stream,
                     (const float4*)w2, (ushort4*)w2b, (int)((size_t)NEXP * DDIM * HDIM / 4));
  hipLaunchKernelGGL(cvt_bf16_k, dim3(2048), dim3(256), 0, stream,
                     (const float4*)x, (ushort4*)xb, (int)((size_t)M_TOK * DDIM / 4));
  hipLaunchKernelGGL(router_k, dim3(M_TOK / 4), dim3(256), 0, stream, x, rw, wgt, eid, counts);
  hipLaunchKernelGGL(offsets_k, dim3(1), dim3(64), 0, stream, counts, offs, tile2exp, tilerow, ntiles);
  hipLaunchKernelGGL(scatter_k, dim3((M_TOK + 255) / 256), dim3(256), 0, stream, eid, offs, cursors, tok, slot);
  hipLaunchKernelGGL(gemm1_k, dim3(MAXTILES, NB1), dim3(512), 0, stream, xb, w1b, tok, tile2exp, tilerow, ntiles, h);
  hipLaunchKernelGGL(gemm2_k, dim3(MAXTILES, NB2), dim3(512), 0, stream, h, w2b, tile2exp, tilerow, ntiles, yp);
  hipLaunchKernelGGL(combine_k, dim3(M_TOK * (DDIM / 8) / 256), dim3(256), 0, stream, yp, wgt, slot, bias, out);
}

// Round 3
// 751.990 us; speedup vs baseline: 1.1103x; 1.0153x over previous
//
#include <hip/hip_runtime.h>
#include <hip/hip_bf16.h>
#include <stdint.h>

#define M_TOK 4096
#define DDIM  2048
#define HDIM  2816
#define NEXP  8
#define PMAX  10240     // 40 * 256 >= 8192 + 8*255
#define MAXTILES 40
#define CVW   8         // extra grid.x rows in gemm1 for w2 conversion
#define NB1   22        // HDIM / 128 gate-col blocks
#define MAXT2 80        // 128-row tiles for gemm2
#define NB2   8         // DDIM / 256
#define NT1   64        // DDIM / 32
#define NT2   88        // HDIM / 32

typedef __attribute__((ext_vector_type(8))) short short8;
typedef __attribute__((ext_vector_type(4))) float f32x4;

#define GLD16(g, l) __builtin_amdgcn_global_load_lds(                              \
    (const __attribute__((address_space(1))) unsigned int*)(g),                    \
    (__attribute__((address_space(3))) unsigned int*)(l), 16, 0, 0)

#define VMCNT(n) asm volatile("s_waitcnt vmcnt(" #n ")" ::: "memory")

__device__ __forceinline__ unsigned short f2bf(float f) {
  unsigned int u = __float_as_uint(f);
  u += 0x7fffu + ((u >> 16) & 1u);
  return (unsigned short)(u >> 16);
}
__device__ __forceinline__ float bf2f(unsigned short u) {
  return __uint_as_float(((unsigned)u) << 16);
}

// ---------------- fp32 -> bf16 bulk convert (w1 only now) ----------------
__global__ void cvt_bf16_k(const float4* __restrict__ in, ushort4* __restrict__ out, int n4) {
  int stride = gridDim.x * blockDim.x;
  for (int i = blockIdx.x * blockDim.x + threadIdx.x; i < n4; i += stride) {
    float4 v = in[i];
    ushort4 o;
    o.x = f2bf(v.x); o.y = f2bf(v.y); o.z = f2bf(v.z); o.w = f2bf(v.w);
    out[i] = o;
  }
}

// ---------------- init ----------------
__global__ void init_k(int* __restrict__ tok, int* __restrict__ counts, int* __restrict__ cursors) {
  int i = blockIdx.x * blockDim.x + threadIdx.x;
  if (i < PMAX) tok[i] = -1;
  if (i < NEXP) { counts[i] = 0; cursors[i] = 0; }
}

// ---------------- router (fused x->bf16 conversion) ----------------
__global__ __launch_bounds__(256) void router_k(const float4* __restrict__ x4,
                                                const float4* __restrict__ rw4,
                                                ushort4* __restrict__ xb4,
                                                float* __restrict__ wgt,
                                                int* __restrict__ eid,
                                                int* __restrict__ counts) {
  int lane = threadIdx.x & 63;
  int wv = threadIdx.x >> 6;
  int t = blockIdx.x * 4 + wv;
  int base = t * (DDIM / 4);
  float acc[NEXP];
#pragma unroll
  for (int e = 0; e < NEXP; ++e) acc[e] = 0.f;
#pragma unroll
  for (int j = 0; j < DDIM / 4 / 64; ++j) {
    float4 v = x4[base + j * 64 + lane];
    ushort4 o;
    o.x = f2bf(v.x); o.y = f2bf(v.y); o.z = f2bf(v.z); o.w = f2bf(v.w);
    xb4[base + j * 64 + lane] = o;
#pragma unroll
    for (int e = 0; e < NEXP; ++e) {
      float4 w = rw4[e * (DDIM / 4) + j * 64 + lane];
      acc[e] += v.x * w.x + v.y * w.y + v.z * w.z + v.w * w.w;
    }
  }
#pragma unroll
  for (int e = 0; e < NEXP; ++e) {
#pragma unroll
    for (int s = 32; s > 0; s >>= 1) acc[e] += __shfl_xor(acc[e], s, 64);
  }
  if (lane == 0) {
    float mx = acc[0];
#pragma unroll
    for (int e = 1; e < NEXP; ++e) mx = fmaxf(mx, acc[e]);
    float p[NEXP];
#pragma unroll
    for (int e = 0; e < NEXP; ++e) p[e] = expf(acc[e] - mx);
    int e0 = 0; float p0 = p[0];
#pragma unroll
    for (int e = 1; e < NEXP; ++e) if (p[e] > p0) { p0 = p[e]; e0 = e; }
    int e1 = -1; float p1 = -1.f;
#pragma unroll
    for (int e = 0; e < NEXP; ++e) if (e != e0 && p[e] > p1) { p1 = p[e]; e1 = e; }
    float s = p0 + p1;
    wgt[2 * t] = p0 / s; wgt[2 * t + 1] = p1 / s;
    eid[2 * t] = e0;     eid[2 * t + 1] = e1;
    atomicAdd(&counts[e0], 1);
    atomicAdd(&counts[e1], 1);
  }
}

// ---------------- offsets + tile maps (256-row for gemm1, 128-row for gemm2) ----------------
__global__ void offsets_k(const int* __restrict__ counts, int* __restrict__ offs,
                          int* __restrict__ tile2exp, int* __restrict__ tilerow,
                          int* __restrict__ ntiles,
                          int* __restrict__ tile2exp2, int* __restrict__ tilerow2,
                          int* __restrict__ ntiles2) {
  if (threadIdx.x == 0 && blockIdx.x == 0) {
    int o = 0, nt = 0, nt2 = 0;
    for (int e = 0; e < NEXP; ++e) {
      offs[e] = o;
      int c = counts[e];
      int pt = (c + 255) >> 8;
      for (int i = 0; i < pt; ++i) {
        tile2exp[nt] = e; tilerow[nt] = o + i * 256; ++nt;
        tile2exp2[nt2] = e; tilerow2[nt2] = o + i * 256; ++nt2;
        tile2exp2[nt2] = e; tilerow2[nt2] = o + i * 256 + 128; ++nt2;
      }
      o += pt << 8;
    }
    offs[NEXP] = o;
    ntiles[0] = nt;
    ntiles2[0] = nt2;
  }
}

// ---------------- scatter ----------------
__global__ void scatter_k(const int* __restrict__ eid, const int* __restrict__ offs,
                          int* __restrict__ cursors, int* __restrict__ tok,
                          int* __restrict__ slot) {
  int t = blockIdx.x * blockDim.x + threadIdx.x;
  if (t >= M_TOK) return;
#pragma unroll
  for (int k = 0; k < 2; ++k) {
    int e = eid[2 * t + k];
    int p = offs[e] + atomicAdd(&cursors[e], 1);
    tok[p] = t;
    slot[2 * t + k] = p;
  }
}

// =============== GEMM1: 256 slots x (128 gate + 128 up), K=2048 ===============
// 8 waves (2M x 4N), per-wave 128x64. Reg-prefetch pipeline, 4 LDS buffers,
// stage 3-ahead, counted vmcnt. Trailing grid.x blocks convert w2 fp32->bf16.
#define STAGE1(TT)                                                               \
  { size_t kb_ = (size_t)(TT) * 64;                                              \
    char* d_ = ldsp + ((TT) & 3) * 16384;                                        \
    GLD16(aS0 + kb_, d_ + aD0);                                                  \
    GLD16(aS1 + kb_, d_ + aD1);                                                  \
    GLD16(bS0 + kb_, d_ + 65536 + aD0);                                          \
    GLD16(bS1 + kb_, d_ + 65536 + aD1); }

#define DSRD1(TT, AV, BV)                                                        \
  { const char* ab_ = ldsp + ((TT) & 3) * 16384;                                 \
    const char* bb_ = ab_ + 65536;                                               \
    _Pragma("unroll") for (int mi = 0; mi < 8; ++mi)                             \
      AV[mi] = *(const short8*)(ab_ + aoff[mi]);                                 \
    _Pragma("unroll") for (int ni = 0; ni < 4; ++ni)                             \
      BV[ni] = *(const short8*)(bb_ + boff[ni]); }

#define MMA1(AV, BV)                                                             \
  { __builtin_amdgcn_s_setprio(1);                                               \
    _Pragma("unroll") for (int mi = 0; mi < 8; ++mi)                             \
      _Pragma("unroll") for (int ni = 0; ni < 4; ++ni)                           \
        acc[mi][ni] = __builtin_amdgcn_mfma_f32_16x16x32_bf16(AV[mi], BV[ni], acc[mi][ni], 0, 0, 0); \
    __builtin_amdgcn_s_setprio(0); }

#define BODY1(TT, VMN, STG, AVC, BVC, AVN, BVN, RD)                              \
  { VMCNT(VMN);                                                                  \
    __builtin_amdgcn_s_barrier();                                                \
    asm volatile("" ::: "memory");                                               \
    if (STG) STAGE1((TT) + 3);                                                   \
    if (RD) DSRD1((TT) + 1, AVN, BVN);                                           \
    __builtin_amdgcn_sched_barrier(0);                                           \
    MMA1(AVC, BVC); }

__global__ __launch_bounds__(512, 1) void gemm1_k(const unsigned short* __restrict__ xb,
                                                  const unsigned short* __restrict__ w1b,
                                                  const int* __restrict__ tok,
                                                  const int* __restrict__ tile2exp,
                                                  const int* __restrict__ tilerow,
                                                  const int* __restrict__ ntiles,
                                                  unsigned short* __restrict__ h,
                                                  const float4* __restrict__ w2src,
                                                  ushort4* __restrict__ w2b4) {
  __shared__ char ldsp[131072];
  int bx = blockIdx.x;
  if (bx >= MAXTILES) {
    // fused w2 fp32->bf16 conversion on trailing blocks
    int id = (bx - MAXTILES) * NB1 + blockIdx.y;
    const int n4 = NEXP * DDIM * HDIM / 4;
    const int stride = CVW * NB1 * 512;
    for (int i = id * 512 + threadIdx.x; i < n4; i += stride) {
      float4 v = w2src[i];
      ushort4 o;
      o.x = f2bf(v.x); o.y = f2bf(v.y); o.z = f2bf(v.z); o.w = f2bf(v.w);
      w2b4[i] = o;
    }
    return;
  }
  int mt = bx;
  if (mt >= ntiles[0]) return;
  int e = tile2exp[mt], r0 = tilerow[mt];
  int n0 = blockIdx.y * 128;
  int tid = threadIdx.x, lane = tid & 63;
  int wv = tid >> 6, wm = wv >> 2, wn = wv & 3;
  int l15 = lane & 15, g = lane >> 4;

  // staging sources (linear LDS dest, inverse-swizzled global granule)
  int row0 = tid >> 2, g0 = (tid & 3) ^ ((row0 >> 1) & 3);
  int s1i = 512 + tid;
  int row1 = s1i >> 2, g1 = (s1i & 3) ^ ((row1 >> 1) & 3);
  int t0 = tok[r0 + row0]; if (t0 < 0) t0 = 0;
  int t1 = tok[r0 + row1]; if (t1 < 0) t1 = 0;
  const char* aS0 = (const char*)xb + (size_t)t0 * (DDIM * 2) + g0 * 16;
  const char* aS1 = (const char*)xb + (size_t)t1 * (DDIM * 2) + g1 * 16;
  size_t w1r0 = (size_t)e * (2 * HDIM) +
                (row0 < 128 ? (size_t)(n0 + row0) : (size_t)(HDIM + n0 + row0 - 128));
  size_t w1r1 = (size_t)e * (2 * HDIM) +
                (row1 < 128 ? (size_t)(n0 + row1) : (size_t)(HDIM + n0 + row1 - 128));
  const char* bS0 = (const char*)w1b + w1r0 * (DDIM * 2) + g0 * 16;
  const char* bS1 = (const char*)w1b + w1r1 * (DDIM * 2) + g1 * 16;
  int aD0 = tid * 16, aD1 = 8192 + tid * 16;

  int aoff[8], boff[4];
#pragma unroll
  for (int mi = 0; mi < 8; ++mi) {
    int r = wm * 128 + mi * 16 + l15;
    aoff[mi] = r * 64 + ((g ^ ((r >> 1) & 3)) * 16);
  }
#pragma unroll
  for (int ni = 0; ni < 4; ++ni) {
    int r = wn * 64 + ni * 16 + l15;
    boff[ni] = r * 64 + ((g ^ ((r >> 1) & 3)) * 16);
  }

  f32x4 acc[8][4];
#pragma unroll
  for (int mi = 0; mi < 8; ++mi)
#pragma unroll
    for (int ni = 0; ni < 4; ++ni) acc[mi][ni] = (f32x4)(0.f);

  short8 avA[8], bvA[4], avB[8], bvB[4];

  // prologue: stage 0,1,2 (12 loads); wait tile0; read tile0 -> bank A
  STAGE1(0); STAGE1(1); STAGE1(2);
  VMCNT(8);
  __builtin_amdgcn_s_barrier();
  asm volatile("" ::: "memory");
  DSRD1(0, avA, bvA);

  for (int T = 0; T < NT1 - 4; T += 4) {
    BODY1(T + 0, 4, 1, avA, bvA, avB, bvB, 1);
    BODY1(T + 1, 4, 1, avB, bvB, avA, bvA, 1);
    BODY1(T + 2, 4, 1, avA, bvA, avB, bvB, 1);
    BODY1(T + 3, 4, 1, avB, bvB, avA, bvA, 1);
  }
  BODY1(NT1 - 4, 4, 1, avA, bvA, avB, bvB, 1);   // T=60: stages 63, reads 61
  BODY1(NT1 - 3, 4, 0, avB, bvB, avA, bvA, 1);   // reads 62
  BODY1(NT1 - 2, 0, 0, avA, bvA, avB, bvB, 1);   // reads 63
  BODY1(NT1 - 1, 0, 0, avB, bvB, avA, bvA, 0);   // MFMA only

  // epilogue: cross-wave GLU pairing through LDS (f32 [256][128], XOR-swizzled)
  __syncthreads();
  float* xch = (float*)ldsp;
  int rbase = (lane >> 4) * 4;
  if (wn >= 2) {
    int uc0 = (wn - 2) * 64;
#pragma unroll
    for (int mi = 0; mi < 8; ++mi)
#pragma unroll
      for (int ni = 0; ni < 4; ++ni)
#pragma unroll
        for (int j = 0; j < 4; ++j) {
          int r = wm * 128 + mi * 16 + rbase + j;
          int c = uc0 + ni * 16 + l15;
          int cs = c ^ ((r & 3) << 2) ^ ((r & 1) << 4);
          xch[r * 128 + cs] = acc[mi][ni][j];
        }
  }
  __syncthreads();
  if (wn < 2) {
#pragma unroll
    for (int mi = 0; mi < 8; ++mi)
#pragma unroll
      for (int ni = 0; ni < 4; ++ni)
#pragma unroll
        for (int j = 0; j < 4; ++j) {
          int r = wm * 128 + mi * 16 + rbase + j;
          int c = wn * 64 + ni * 16 + l15;
          int cs = c ^ ((r & 3) << 2) ^ ((r & 1) << 4);
          float gg = acc[mi][ni][j];
          float u = xch[r * 128 + cs];
          float sv = gg / (1.f + expf(-gg));
          h[(size_t)(r0 + r) * HDIM + n0 + c] = f2bf(sv * u);
        }
  }
}

// =============== GEMM2: 128 slots x 256 D-cols, K=2816, yp bf16 ===============
// 8 waves (2M x 4N), per-wave 64x64. Same pipeline; 3 loads/body.
#define STAGE2(TT)                                                               \
  { size_t kb_ = (size_t)(TT) * 64;                                              \
    GLD16(aS0 + kb_, ldsp + ((TT) & 3) * 8192 + aD0);                            \
    GLD16(bS0 + kb_, ldsp + 32768 + ((TT) & 3) * 16384 + bD0);                   \
    GLD16(bS1 + kb_, ldsp + 32768 + ((TT) & 3) * 16384 + bD1); }

#define DSRD2(TT, AV, BV)                                                        \
  { const char* ab_ = ldsp + ((TT) & 3) * 8192;                                  \
    const char* bb_ = ldsp + 32768 + ((TT) & 3) * 16384;                         \
    _Pragma("unroll") for (int mi = 0; mi < 4; ++mi)                             \
      AV[mi] = *(const short8*)(ab_ + aoff[mi]);                                 \
    _Pragma("unroll") for (int ni = 0; ni < 4; ++ni)                             \
      BV[ni] = *(const short8*)(bb_ + boff[ni]); }

#define MMA2(AV, BV)                                                             \
  { __builtin_amdgcn_s_setprio(1);                                               \
    _Pragma("unroll") for (int mi = 0; mi < 4; ++mi)                             \
      _Pragma("unroll") for (int ni = 0; ni < 4; ++ni)                           \
        acc[mi][ni] = __builtin_amdgcn_mfma_f32_16x16x32_bf16(AV[mi], BV[ni], acc[mi][ni], 0, 0, 0); \
    __builtin_amdgcn_s_setprio(0); }

#define BODY2(TT, VMN, STG, AVC, BVC, AVN, BVN, RD)                              \
  { VMCNT(VMN);                                                                  \
    __builtin_amdgcn_s_barrier();                                                \
    asm volatile("" ::: "memory");                                               \
    if (STG) STAGE2((TT) + 3);                                                   \
    if (RD) DSRD2((TT) + 1, AVN, BVN);                                           \
    __builtin_amdgcn_sched_barrier(0);                                           \
    MMA2(AVC, BVC); }

__global__ __launch_bounds__(512, 1) void gemm2_k(const unsigned short* __restrict__ h,
                                                  const unsigned short* __restrict__ w2b,
                                                  const int* __restrict__ tile2exp2,
                                                  const int* __restrict__ tilerow2,
                                                  const int* __restrict__ ntiles2,
                                                  unsigned short* __restrict__ yp) {
  __shared__ char ldsp[98304];
  int mt = blockIdx.x;
  if (mt >= ntiles2[0]) return;
  int e = tile2exp2[mt], r0 = tilerow2[mt];
  int n0 = blockIdx.y * 256;
  int tid = threadIdx.x, lane = tid & 63;
  int wv = tid >> 6, wm = wv >> 2, wn = wv & 3;
  int l15 = lane & 15, g = lane >> 4;

  int rowa = tid >> 2, ga = (tid & 3) ^ ((rowa >> 1) & 3);          // A: 128 rows, 1 load
  int rb0 = tid >> 2, gb0 = (tid & 3) ^ ((rb0 >> 1) & 3);          // B: 256 rows, 2 loads
  int s1i = 512 + tid;
  int rb1 = s1i >> 2, gb1 = (s1i & 3) ^ ((rb1 >> 1) & 3);
  const char* aS0 = (const char*)h + (size_t)(r0 + rowa) * (HDIM * 2) + ga * 16;
  const char* bS0 = (const char*)w2b + ((size_t)e * DDIM + n0 + rb0) * (HDIM * 2) + gb0 * 16;
  const char* bS1 = (const char*)w2b + ((size_t)e * DDIM + n0 + rb1) * (HDIM * 2) + gb1 * 16;
  int aD0 = tid * 16, bD0 = tid * 16, bD1 = 8192 + tid * 16;

  int aoff[4], boff[4];
#pragma unroll
  for (int mi = 0; mi < 4; ++mi) {
    int r = wm * 64 + mi * 16 + l15;
    aoff[mi] = r * 64 + ((g ^ ((r >> 1) & 3)) * 16);
  }
#pragma unroll
  for (int ni = 0; ni < 4; ++ni) {
    int r = wn * 64 + ni * 16 + l15;
    boff[ni] = r * 64 + ((g ^ ((r >> 1) & 3)) * 16);
  }

  f32x4 acc[4][4];
#pragma unroll
  for (int mi = 0; mi < 4; ++mi)
#pragma unroll
    for (int ni = 0; ni < 4; ++ni) acc[mi][ni] = (f32x4)(0.f);

  short8 avA[4], bvA[4], avB[4], bvB[4];

  STAGE2(0); STAGE2(1); STAGE2(2);
  VMCNT(6);
  __builtin_amdgcn_s_barrier();
  asm volatile("" ::: "memory");
  DSRD2(0, avA, bvA);

  for (int T = 0; T < NT2 - 4; T += 4) {
    BODY2(T + 0, 3, 1, avA, bvA, avB, bvB, 1);
    BODY2(T + 1, 3, 1, avB, bvB, avA, bvA, 1);
    BODY2(T + 2, 3, 1, avA, bvA, avB, bvB, 1);
    BODY2(T + 3, 3, 1, avB, bvB, avA, bvA, 1);
  }
  BODY2(NT2 - 4, 3, 1, avA, bvA, avB, bvB, 1);   // T=84: stages 87, reads 85
  BODY2(NT2 - 3, 3, 0, avB, bvB, avA, bvA, 1);   // reads 86
  BODY2(NT2 - 2, 0, 0, avA, bvA, avB, bvB, 1);   // reads 87
  BODY2(NT2 - 1, 0, 0, avB, bvB, avA, bvA, 0);   // MFMA only

  int rbase = (lane >> 4) * 4;
#pragma unroll
  for (int mi = 0; mi < 4; ++mi)
#pragma unroll
    for (int ni = 0; ni < 4; ++ni)
#pragma unroll
      for (int j = 0; j < 4; ++j) {
        int r = r0 + wm * 64 + mi * 16 + rbase + j;
        int c = n0 + wn * 64 + ni * 16 + l15;
        yp[(size_t)r * DDIM + c] = f2bf(acc[mi][ni][j]);
      }
}

// ---------------- combine: y = w0*yp[s0] + w1*yp[s1] + bias ----------------
__global__ void combine_k(const unsigned short* __restrict__ yp, const float* __restrict__ wgt,
                          const int* __restrict__ slot, const float* __restrict__ bias,
                          float* __restrict__ out) {
  int idx = blockIdx.x * blockDim.x + threadIdx.x;
  int t = idx >> 8, q = (idx & 255) * 8;
  float w0 = wgt[2 * t], w1 = wgt[2 * t + 1];
  int s0 = slot[2 * t], s1 = slot[2 * t + 1];
  short8 a8 = *(const short8*)(yp + (size_t)s0 * DDIM + q);
  short8 b8 = *(const short8*)(yp + (size_t)s1 * DDIM + q);
  float* op = out + (size_t)t * DDIM + q;
#pragma unroll
  for (int k = 0; k < 8; ++k) {
    float av = bf2f((unsigned short)a8[k]);
    float bv = bf2f((unsigned short)b8[k]);
    op[k] = w0 * av + w1 * bv + bias[q + k];
  }
}

extern "C" void kernel_launch(void* const* d_in, const int* in_sizes, int n_in,
                              void* d_out, int out_size, void* d_ws, size_t ws_size,
                              hipStream_t stream) {
  const float* x    = (const float*)d_in[0];
  const float* w1   = (const float*)d_in[1];
  const float* w2   = (const float*)d_in[2];
  const float* rw   = (const float*)d_in[3];
  const float* bias = (const float*)d_in[4];
  float* out = (float*)d_out;

  char* ws = (char*)d_ws;
  size_t off = 0;
  auto alloc = [&](size_t bytes) -> void* {
    void* p = ws + off;
    off = (off + bytes + 255) & ~(size_t)255;
    return p;
  };
  unsigned short* w1b = (unsigned short*)alloc((size_t)NEXP * 2 * HDIM * DDIM * 2);
  unsigned short* w2b = (unsigned short*)alloc((size_t)NEXP * DDIM * HDIM * 2);
  unsigned short* xb  = (unsigned short*)alloc((size_t)M_TOK * DDIM * 2);
  unsigned short* h   = (unsigned short*)alloc((size_t)PMAX * HDIM * 2);
  unsigned short* yp  = (unsigned short*)alloc((size_t)PMAX * DDIM * 2);
  float* wgt          = (float*)alloc((size_t)M_TOK * 2 * 4);
  int* eid            = (int*)alloc((size_t)M_TOK * 2 * 4);
  int* slot           = (int*)alloc((size_t)M_TOK * 2 * 4);
  int* tok            = (int*)alloc((size_t)PMAX * 4);
  int* counts         = (int*)alloc(64 * 4);
  int* cursors        = (int*)alloc(64 * 4);
  int* offs           = (int*)alloc(64 * 4);
  int* ntiles         = (int*)alloc(64 * 4);
  int* ntiles2        = (int*)alloc(64 * 4);
  int* tile2exp       = (int*)alloc(128 * 4);
  int* tilerow        = (int*)alloc(128 * 4);
  int* tile2exp2      = (int*)alloc(128 * 4);
  int* tilerow2       = (int*)alloc(128 * 4);

  hipLaunchKernelGGL(init_k, dim3((PMAX + 255) / 256), dim3(256), 0, stream, tok, counts, cursors);
  hipLaunchKernelGGL(cvt_bf16_k, dim3(2048), dim3(256), 0, stream,
                     (const float4*)w1, (ushort4*)w1b, (int)((size_t)NEXP * 2 * HDIM * DDIM / 4));
  hipLaunchKernelGGL(router_k, dim3(M_TOK / 4), dim3(256), 0, stream,
                     (const float4*)x, (const float4*)rw, (ushort4*)xb, wgt, eid, counts);
  hipLaunchKernelGGL(offsets_k, dim3(1), dim3(64), 0, stream, counts, offs,
                     tile2exp, tilerow, ntiles, tile2exp2, tilerow2, ntiles2);
  hipLaunchKernelGGL(scatter_k, dim3((M_TOK + 255) / 256), dim3(256), 0, stream, eid, offs, cursors, tok, slot);
  hipLaunchKernelGGL(gemm1_k, dim3(MAXTILES + CVW, NB1), dim3(512), 0, stream,
                     xb, w1b, tok, tile2exp, tilerow, ntiles, h, (const float4*)w2, (ushort4*)w2b);
  hipLaunchKernelGGL(gemm2_k, dim3(MAXT2, NB2), dim3(512), 0, stream,
                     h, w2b, tile2exp2, tilerow2, ntiles2, yp);
  hipLaunchKernelGGL(combine_k, dim3(M_TOK * (DDIM / 8) / 256), dim3(256), 0, stream, yp, wgt, slot, bias, out);
}